// Round 15
// baseline (406.860 us; speedup 1.0000x reference)
//
#include <hip/hip_runtime.h>
#include <hip/hip_bf16.h>
#include <stdint.h>

// ---------- types ----------
typedef __bf16 bf16x8 __attribute__((ext_vector_type(8)));
typedef float  f32x4  __attribute__((ext_vector_type(4)));
typedef unsigned short u16x8 __attribute__((ext_vector_type(8)));
typedef unsigned short u16x4 __attribute__((ext_vector_type(4)));
typedef _Float16 f16x4 __attribute__((ext_vector_type(4)));

#define HS    1024     // hidden size
#define FOURH 4096
#define SEQ   512
#define BATCH 64

#define BAR()  asm volatile("s_barrier" ::: "memory")
#define VMW(n) asm volatile("s_waitcnt vmcnt(" #n ")" ::: "memory")

// manual round-to-nearest-even f32 -> bf16 bits
__device__ __forceinline__ unsigned short f2bf(float f) {
    unsigned u = __builtin_bit_cast(unsigned, f);
    u = (u + 0x7FFFu + ((u >> 16) & 1u)) >> 16;
    return (unsigned short)u;
}

__device__ __forceinline__ void gload_lds16(const void* g, void* l) {
    __builtin_amdgcn_global_load_lds(
        (const __attribute__((address_space(1))) void*)g,
        (__attribute__((address_space(3))) void*)l, 16, 0, 0);
}

__device__ __forceinline__ float fsigmoid(float v) {
    return __builtin_amdgcn_rcpf(1.f + __expf(-v));
}
__device__ __forceinline__ float ftanh(float v) {
    return 1.f - 2.f * __builtin_amdgcn_rcpf(1.f + __expf(2.f * v));
}

// ---------- kernel 1: x (f32) -> Xb (bf16) ----------
__global__ __launch_bounds__(256) void convert_x(const float* __restrict__ x,
                                                 unsigned short* __restrict__ xb,
                                                 long n8) {
    long i = (long)blockIdx.x * blockDim.x + threadIdx.x;
    long stride = (long)gridDim.x * blockDim.x;
    for (; i < n8; i += stride) {
        const float4* p = (const float4*)(x + i * 8);
        float4 a = p[0], b = p[1];
        u16x8 o;
        o[0] = f2bf(a.x); o[1] = f2bf(a.y); o[2] = f2bf(a.z); o[3] = f2bf(a.w);
        o[4] = f2bf(b.x); o[5] = f2bf(b.y); o[6] = f2bf(b.z); o[7] = f2bf(b.w);
        *(u16x8*)(xb + i * 8) = o;
    }
}

// ---------- kernel 2: U [1024][4096] f32 -> Ut[perm(n)][k] bf16 --------------
// perm(gate*1024+h) = (h>>4)*64 + gate*16 + (h&15): 64-col slice = 16 h x 4 g.
__global__ __launch_bounds__(256) void transpose_u(const float* __restrict__ U,
                                                   unsigned short* __restrict__ Ut) {
    __shared__ float tile[32][33];
    int bx = blockIdx.x;            // 4096 blocks
    int tn = bx >> 5;               // n tile
    int tk = bx & 31;               // k tile
    int c = threadIdx.x & 31;
    int r = threadIdx.x >> 5;
#pragma unroll
    for (int i = 0; i < 4; ++i) {
        int k = tk * 32 + r + i * 8;
        tile[r + i * 8][c] = U[(size_t)k * FOURH + tn * 32 + c];
    }
    __syncthreads();
#pragma unroll
    for (int i = 0; i < 4; ++i) {
        int nl = r + i * 8;
        int n = tn * 32 + nl;
        int gate = n >> 10, h = n & 1023;
        int pn = ((h >> 4) << 6) | (gate << 4) | (h & 15);
        Ut[(size_t)pn * HS + tk * 32 + c] = f2bf(tile[c][nl]);
    }
}

// ---------- kernel 3: 256x256, BK=64, 16 waves (4Mx4N), 4 waves/SIMD ---------
// Same 256^2 tile/LDS/swizzle as r8/r14 (FETCH unchanged, 0 conflicts), but
// 16 small waves -> 4 waves/SIMD for wave-level LDS<->MFMA overlap.
// Per wave/tile: 4 staging loads in 2 groups SG(.,ks); R1{read ks0, SG(t+1,1),
// 16 MFMA, VMW(2)}, R2{read ks1, SG(t+2,0), 16 MFMA, VMW(2)}. Each VMW(2)
// retires loads issued one region earlier; queue 2<->4; never drains till tail.
// SG(t+2,0) same-buffer write is WAR-safe: ks0/ks1 slots disjoint + R1-end BAR.
__global__ __launch_bounds__(1024, 4) void gemm_gates16(
    const unsigned short* __restrict__ Xb,   // [B*S][1024] bf16
    const unsigned short* __restrict__ Ut,   // [4096 perm][1024] bf16
    const float* __restrict__ bias,          // [4096] original order
    _Float16* __restrict__ gates,            // packed [rows/4][3][4096]
    int lg2chunk, int s0) {
    __shared__ unsigned short LDSU[65536];   // 128KB: buf(t&1)*32768; A@0, B@+16384

    int nwg = gridDim.x;
    int bid = blockIdx.x;
    int wg = (bid & 7) * (nwg >> 3) + (bid >> 3);
    int mt = wg >> 4;            // 16 n-tiles (4096/256)
    int nt = wg & 15;

    int tid = threadIdx.x;
    int w = tid >> 6, l = tid & 63;
    int wr = w >> 2, wc = w & 3;       // wave grid 4 (M) x 4 (N)
    int lr = l & 15, lg = l >> 4;

    const int m0 = mt * 256, n0 = nt * 256;
    const int cmask = (1 << lg2chunk) - 1;

    // ds_read offset within a 16x32 subtile (ushort units), st_16x32 swizzle
    const int rdo = lr * 32 + ((lg * 8) ^ ((lr & 8) << 1));
    // staging lane geometry
    const int srow = l >> 2;
    const int skin = ((l & 3) * 8) ^ (((l >> 5) & 1) << 4);

    // staging: wave w owns rowgroup w (16 rows) of both A and B
    const unsigned short* pA;
    const unsigned short* pB;
    {
        int mrow = m0 + w * 16 + srow;
        int b = mrow >> lg2chunk, sl2 = mrow & cmask;
        pA = Xb + (size_t)(b * SEQ + s0 + sl2) * HS + skin;
        pB = Ut + (size_t)(n0 + w * 16 + srow) * HS + skin;
    }

    f32x4 acc[4][4];
#pragma unroll
    for (int mi = 0; mi < 4; ++mi)
#pragma unroll
        for (int ni = 0; ni < 4; ++ni) acc[mi][ni] = 0.f;

#define SG(T, KS) { \
    gload_lds16(pA + (T) * 64 + (KS) * 32, \
        &LDSU[(((T) & 1) << 15) + (w * 2 + (KS)) * 512]); \
    gload_lds16(pB + (T) * 64 + (KS) * 32, \
        &LDSU[(((T) & 1) << 15) + 16384 + (w * 2 + (KS)) * 512]); }

    bf16x8 av[4], bv[4];

#define RDA(KS) \
    _Pragma("unroll") for (int mi = 0; mi < 4; ++mi) \
        av[mi] = *(const bf16x8*)(buf + (((wr * 4 + mi) * 2) + (KS)) * 512 + rdo)
#define RDB(KS) \
    _Pragma("unroll") for (int ni = 0; ni < 4; ++ni) \
        bv[ni] = *(const bf16x8*)(buf + 16384 + (((wc * 4 + ni) * 2) + (KS)) * 512 + rdo)
#define MMQ() \
    __builtin_amdgcn_s_setprio(1); \
    _Pragma("unroll") for (int mi = 0; mi < 4; ++mi) \
    _Pragma("unroll") for (int ni = 0; ni < 4; ++ni) \
        acc[mi][ni] = __builtin_amdgcn_mfma_f32_16x16x32_bf16( \
            av[mi], bv[ni], acc[mi][ni], 0, 0, 0); \
    __builtin_amdgcn_s_setprio(0)

    // prologue: tile 0 both halves + tile 1 ks0; confirm tile 0 (leave 2)
    SG(0, 0); SG(0, 1); SG(1, 0);
    VMW(2); BAR();

    for (int t = 0; t < 16; ++t) {
        const unsigned short* buf = &LDSU[(t & 1) << 15];
        // ---- R1: ks=0; stage SG(t+1, ks1) ----
        RDA(0); RDB(0);
        if (t < 15) SG(t + 1, 1);
        MMQ();
        if (t < 15) { VMW(2); } else { VMW(0); }
        BAR();
        // ---- R2: ks=1; stage SG(t+2, ks0) ----
        RDA(1); RDB(1);
        if (t < 14) SG(t + 2, 0);
        MMQ();
        if (t < 14) { VMW(2); }
        BAR();
    }

    // ---- epilogue: fused p = sig(i)*tanh(g); store p,f,o planes ----
    // ni = gate; lane h = (n0/64 + wc)*16 + lr for all ni.
    const int hh = ((n0 >> 6) + wc) * 16 + lr;
    const float bi = bias[hh], bf_ = bias[1024 + hh];
    const float bg = bias[2048 + hh], bo = bias[3072 + hh];
#pragma unroll
    for (int mi = 0; mi < 4; ++mi) {
        size_t rg = (size_t)(((m0 + wr * 64 + mi * 16) >> 2) + lg);
        u16x4 pkP, pkF, pkO;
#pragma unroll
        for (int r = 0; r < 4; ++r) {
            float iv = fsigmoid(acc[mi][0][r] + bi);
            float fv = fsigmoid(acc[mi][1][r] + bf_);
            float gv = ftanh(acc[mi][2][r] + bg);
            float ov = fsigmoid(acc[mi][3][r] + bo);
            float pv = iv * gv;
            pkP[r] = __builtin_bit_cast(unsigned short, (_Float16)pv);
            pkF[r] = __builtin_bit_cast(unsigned short, (_Float16)fv);
            pkO[r] = __builtin_bit_cast(unsigned short, (_Float16)ov);
        }
        _Float16* gp = gates + rg * 12288 + hh * 4;
        *(u16x4*)(gp)        = pkP;
        *(u16x4*)(gp + 4096) = pkF;
        *(u16x4*)(gp + 8192) = pkO;
    }
#undef SG
#undef RDA
#undef RDB
#undef MMQ
}

// ---------- kernel 4: recurrence on p,f,o planes, one thread per (b,h) -------
__global__ __launch_bounds__(256) void lstm_recur(
    const _Float16* __restrict__ gates,  // [rg][{p,f,o}][4096] f16
    float* __restrict__ out,             // d_out base (f32)
    float* __restrict__ cstate,          // [65536]
    int chunk, int s0) {
    int t = blockIdx.x * 256 + threadIdx.x;  // 0..65535
    int b = t >> 10, h = t & 1023;
    float c = (s0 == 0) ? 0.f : cstate[t];
    const _Float16* gp = gates + (size_t)((b * chunk) >> 2) * 12288 + h * 4;
    float* op = out + (size_t)(b * SEQ + s0) * HS + h;
    float hv = 0.f;
    const int ng = chunk >> 2;               // row-groups of 4 steps
    int g4 = 0;
    for (; g4 + 1 < ng; g4 += 2) {
        f16x4 pv[2], fv[2], ov[2];
#pragma unroll
        for (int u = 0; u < 2; ++u) {
            const _Float16* q = gp + (size_t)(g4 + u) * 12288;
            pv[u] = *(const f16x4*)(q);
            fv[u] = *(const f16x4*)(q + 4096);
            ov[u] = *(const f16x4*)(q + 8192);
        }
#pragma unroll
        for (int u = 0; u < 2; ++u) {
#pragma unroll
            for (int r = 0; r < 4; ++r) {
                c = (float)fv[u][r] * c + (float)pv[u][r];
                float th = ftanh(c);
                hv = (float)ov[u][r] * th;
                op[(size_t)((g4 + u) * 4 + r) * HS] = hv;
            }
        }
    }
    for (; g4 < ng; ++g4) {                  // tail (odd ng)
        const _Float16* q = gp + (size_t)g4 * 12288;
        f16x4 pv = *(const f16x4*)(q);
        f16x4 fv = *(const f16x4*)(q + 4096);
        f16x4 ov = *(const f16x4*)(q + 8192);
#pragma unroll
        for (int r = 0; r < 4; ++r) {
            c = (float)fv[r] * c + (float)pv[r];
            float th = ftanh(c);
            hv = (float)ov[r] * th;
            op[(size_t)(g4 * 4 + r) * HS] = hv;
        }
    }
    cstate[t] = c;
    if (s0 + chunk == SEQ) {
        out[(size_t)BATCH * SEQ * HS + t] = hv;                      // h_T
        out[(size_t)BATCH * SEQ * HS + BATCH * HS + t] = c;          // c_T
    }
}

// ---------- launcher ----------
extern "C" void kernel_launch(void* const* d_in, const int* in_sizes, int n_in,
                              void* d_out, int out_size, void* d_ws, size_t ws_size,
                              hipStream_t stream) {
    const float* x    = (const float*)d_in[0];
    const float* U    = (const float*)d_in[1];
    const float* bias = (const float*)d_in[2];
    float* out = (float*)d_out;
    char*  ws  = (char*)d_ws;

    // ws layout
    unsigned short* Xb = (unsigned short*)ws;                   // 64MB  bf16 x
    unsigned short* Ut = (unsigned short*)(ws + 67108864);      // 8MB   bf16 U^T
    float* cstate      = (float*)(ws + 75497472);               // 256KB
    _Float16* gates    = (_Float16*)(ws + 75759616);            // chunk*0.375MB
    const size_t fixed = 75759616;

    int chunk = 512;
    while (chunk > 4 && fixed + (size_t)BATCH * chunk * 6144 > ws_size)
        chunk >>= 1;
    int lg2 = 31 - __builtin_clz(chunk);

    convert_x<<<2048, 256, 0, stream>>>(x, Xb, (long)BATCH * SEQ * HS / 8);
    transpose_u<<<4096, 256, 0, stream>>>(U, Ut);

    for (int s0 = 0; s0 < SEQ; s0 += chunk) {
        int mtiles = (BATCH * chunk) / 256;
        gemm_gates16<<<mtiles * 16, 1024, 0, stream>>>(Xb, Ut, bias, gates, lg2, s0);
        lstm_recur<<<256, 256, 0, stream>>>(gates, out, cstate, chunk, s0);
    }
}

// Round 16
// 377.007 us; speedup vs baseline: 1.0792x; 1.0792x over previous
//
#include <hip/hip_runtime.h>
#include <hip/hip_bf16.h>
#include <stdint.h>

// ---------- types ----------
typedef __bf16 bf16x8 __attribute__((ext_vector_type(8)));
typedef float  f32x4  __attribute__((ext_vector_type(4)));
typedef unsigned short u16x8 __attribute__((ext_vector_type(8)));
typedef unsigned short u16x4 __attribute__((ext_vector_type(4)));
typedef _Float16 f16x4 __attribute__((ext_vector_type(4)));

#define HS    1024     // hidden size
#define FOURH 4096
#define SEQ   512
#define BATCH 64

#define BAR()  asm volatile("s_barrier" ::: "memory")
#define VMW(n) asm volatile("s_waitcnt vmcnt(" #n ")" ::: "memory")

// manual round-to-nearest-even f32 -> bf16 bits
__device__ __forceinline__ unsigned short f2bf(float f) {
    unsigned u = __builtin_bit_cast(unsigned, f);
    u = (u + 0x7FFFu + ((u >> 16) & 1u)) >> 16;
    return (unsigned short)u;
}

__device__ __forceinline__ void gload_lds16(const void* g, void* l) {
    __builtin_amdgcn_global_load_lds(
        (const __attribute__((address_space(1))) void*)g,
        (__attribute__((address_space(3))) void*)l, 16, 0, 0);
}

__device__ __forceinline__ float fsigmoid(float v) {
    return __builtin_amdgcn_rcpf(1.f + __expf(-v));
}
__device__ __forceinline__ float ftanh(float v) {
    return 1.f - 2.f * __builtin_amdgcn_rcpf(1.f + __expf(2.f * v));
}

// ---------- kernel 1: x (f32) -> Xb (bf16) ----------
__global__ __launch_bounds__(256) void convert_x(const float* __restrict__ x,
                                                 unsigned short* __restrict__ xb,
                                                 long n8) {
    long i = (long)blockIdx.x * blockDim.x + threadIdx.x;
    long stride = (long)gridDim.x * blockDim.x;
    for (; i < n8; i += stride) {
        const float4* p = (const float4*)(x + i * 8);
        float4 a = p[0], b = p[1];
        u16x8 o;
        o[0] = f2bf(a.x); o[1] = f2bf(a.y); o[2] = f2bf(a.z); o[3] = f2bf(a.w);
        o[4] = f2bf(b.x); o[5] = f2bf(b.y); o[6] = f2bf(b.z); o[7] = f2bf(b.w);
        *(u16x8*)(xb + i * 8) = o;
    }
}

// ---------- kernel 2: U [1024][4096] f32 -> Ut[perm(n)][k] bf16 --------------
// Column permutation interleaves gates: perm(gate*1024+h) = (h>>4)*64 +
// gate*16 + (h&15), so each 64-col slice = 16 h's x 4 gates (epilogue fusion).
__global__ __launch_bounds__(256) void transpose_u(const float* __restrict__ U,
                                                   unsigned short* __restrict__ Ut) {
    __shared__ float tile[32][33];
    int bx = blockIdx.x;            // 4096 blocks
    int tn = bx >> 5;               // n tile
    int tk = bx & 31;               // k tile
    int c = threadIdx.x & 31;
    int r = threadIdx.x >> 5;
#pragma unroll
    for (int i = 0; i < 4; ++i) {
        int k = tk * 32 + r + i * 8;
        tile[r + i * 8][c] = U[(size_t)k * FOURH + tn * 32 + c];
    }
    __syncthreads();
#pragma unroll
    for (int i = 0; i < 4; ++i) {
        int nl = r + i * 8;
        int n = tn * 32 + nl;
        int gate = n >> 10, h = n & 1023;
        int pn = ((h >> 4) << 6) | (gate << 4) | (h & 15);
        Ut[(size_t)pn * HS + tk * 32 + c] = f2bf(tile[c][nl]);
    }
}

// ---------- kernel 3: 256x256, BK=64 GEMM (r8 core) + fused p=i*g epilogue ---
// Gate-interleaved B: lane lr holds h = (n0/64+wc)*16+lr for ALL ni=gate.
// Epilogue computes p=sig(i)*tanh(g), f, o in-register; stores 3 f16 planes
// [rg][{p,f,o}][4096] (25% less gates traffic than 4-gate storage).
__global__ __launch_bounds__(512, 1) void gemm_gates8(
    const unsigned short* __restrict__ Xb,   // [B*S][1024] bf16
    const unsigned short* __restrict__ Ut,   // [4096 perm][1024] bf16
    const float* __restrict__ bias,          // [4096] original order
    _Float16* __restrict__ gates,            // packed [rows/4][3][4096]
    int lg2chunk, int s0) {
    __shared__ unsigned short LDSU[65536];   // 128KB: buf(t&1)*32768; A@0, B@+16384

    int nwg = gridDim.x;
    int bid = blockIdx.x;
    int wg = (bid & 7) * (nwg >> 3) + (bid >> 3);
    int mt = wg >> 4;            // 16 n-tiles (4096/256)
    int nt = wg & 15;

    int tid = threadIdx.x;
    int w = tid >> 6, l = tid & 63;
    int wr = w >> 2, wc = w & 3;       // wave grid 2 (M) x 4 (N)
    int lr = l & 15, lg = l >> 4;

    const int m0 = mt * 256, n0 = nt * 256;
    const int cmask = (1 << lg2chunk) - 1;

    const int rdo = lr * 32 + ((lg * 8) ^ ((lr & 8) << 1));
    const int srow = l >> 2;
    const int skin = ((l & 3) * 8) ^ (((l >> 5) & 1) << 4);

    const unsigned short* pAq[4];
    const unsigned short* pBq[4];
#pragma unroll
    for (int q = 0; q < 4; ++q) {
        int rowg = q * 64 + (w >> 1) * 16 + srow;
        int mrow = m0 + rowg;
        int b = mrow >> lg2chunk, sl2 = mrow & cmask;
        pAq[q] = Xb + (size_t)(b * SEQ + s0 + sl2) * HS + (w & 1) * 32 + skin;
        pBq[q] = Ut + (size_t)(n0 + rowg) * HS + (w & 1) * 32 + skin;
    }
    const int dsub = (w >> 1) * 2 + (w & 1);

    f32x4 acc[8][4];
#pragma unroll
    for (int mi = 0; mi < 8; ++mi)
#pragma unroll
        for (int ni = 0; ni < 4; ++ni) acc[mi][ni] = 0.f;

#define SA(T, Q) gload_lds16(pAq[Q] + (T) * 64, \
        &LDSU[(((T) & 1) << 15) + ((Q) * 8 + dsub) * 512])
#define SB(T, Q) gload_lds16(pBq[Q] + (T) * 64, \
        &LDSU[(((T) & 1) << 15) + 16384 + ((Q) * 8 + dsub) * 512])

    bf16x8 aq[2][4], bn0[2][2], bn1[2][2];

#define RDA(MH) \
    _Pragma("unroll") for (int ks = 0; ks < 2; ++ks) \
    _Pragma("unroll") for (int mi = 0; mi < 4; ++mi) \
        aq[ks][mi] = *(const bf16x8*)(buf + ((wr * 8 + (MH) * 4 + mi) * 2 + ks) * 512 + rdo)
#define RDB(NH, BN) \
    _Pragma("unroll") for (int ks = 0; ks < 2; ++ks) \
    _Pragma("unroll") for (int ni = 0; ni < 2; ++ni) \
        BN[ks][ni] = *(const bf16x8*)(buf + 16384 + ((wc * 4 + (NH) * 2 + ni) * 2 + ks) * 512 + rdo)
#define MMQ(MH, NH, BN) \
    __builtin_amdgcn_s_setprio(1); \
    _Pragma("unroll") for (int ks = 0; ks < 2; ++ks) \
    _Pragma("unroll") for (int mi = 0; mi < 4; ++mi) \
    _Pragma("unroll") for (int ni = 0; ni < 2; ++ni) \
        acc[(MH) * 4 + mi][(NH) * 2 + ni] = __builtin_amdgcn_mfma_f32_16x16x32_bf16( \
            aq[ks][mi], BN[ks][ni], acc[(MH) * 4 + mi][(NH) * 2 + ni], 0, 0, 0); \
    __builtin_amdgcn_s_setprio(0)

    SA(0, 0); SA(0, 2); SB(0, 0); SB(0, 1); SB(0, 2); SB(0, 3); SA(0, 1); SA(0, 3);
    VMW(2); BAR();

    for (int t = 0; t < 16; ++t) {
        const unsigned short* buf = &LDSU[(t & 1) << 15];
        // ---- region 1: Q(0,0) + Q(0,1); stage ALL R1-needs of t+1 ----
        RDA(0);
        RDB(0, bn0);
        if (t < 15) { SA(t + 1, 0); SA(t + 1, 2); }
        MMQ(0, 0, bn0);
        RDB(1, bn1);
        if (t < 15) { SB(t + 1, 0); SB(t + 1, 1); SB(t + 1, 2); SB(t + 1, 3); }
        MMQ(0, 1, bn1);
        if (t < 15) { VMW(6); } else { VMW(0); }
        BAR();
        // ---- region 2: Q(1,1) + Q(1,0); stage A1,A3 of t+1 ----
        RDA(1);
        if (t < 15) { SA(t + 1, 1); SA(t + 1, 3); }
        MMQ(1, 1, bn1);
        MMQ(1, 0, bn0);
        if (t < 15) { VMW(2); }
        BAR();
    }

    // ---- epilogue: fused p = sig(i)*tanh(g); store p,f,o planes ----
    // ni = gate (0:i 1:f 2:g 3:o); lane h = (n0/64 + wc)*16 + lr for all ni.
    const int hh = ((n0 >> 6) + wc) * 16 + lr;
    const float bi = bias[hh], bf = bias[1024 + hh];
    const float bg = bias[2048 + hh], bo = bias[3072 + hh];
#pragma unroll
    for (int mi = 0; mi < 8; ++mi) {
        size_t rg = (size_t)(((m0 + wr * 128 + mi * 16) >> 2) + lg);
        u16x4 pkP, pkF, pkO;
#pragma unroll
        for (int r = 0; r < 4; ++r) {
            float iv = fsigmoid(acc[mi][0][r] + bi);
            float fv = fsigmoid(acc[mi][1][r] + bf);
            float gv = ftanh(acc[mi][2][r] + bg);
            float ov = fsigmoid(acc[mi][3][r] + bo);
            float pv = iv * gv;
            pkP[r] = __builtin_bit_cast(unsigned short, (_Float16)pv);
            pkF[r] = __builtin_bit_cast(unsigned short, (_Float16)fv);
            pkO[r] = __builtin_bit_cast(unsigned short, (_Float16)ov);
        }
        _Float16* gp = gates + rg * 12288 + hh * 4;
        *(u16x4*)(gp)        = pkP;
        *(u16x4*)(gp + 4096) = pkF;
        *(u16x4*)(gp + 8192) = pkO;
    }
#undef SA
#undef SB
#undef RDA
#undef RDB
#undef MMQ
}

// ---------- kernel 4: recurrence on p,f,o planes, one thread per (b,h) -------
__global__ __launch_bounds__(256) void lstm_recur(
    const _Float16* __restrict__ gates,  // [rg][{p,f,o}][4096] f16
    float* __restrict__ out,             // d_out base (f32)
    float* __restrict__ cstate,          // [65536]
    int chunk, int s0) {
    int t = blockIdx.x * 256 + threadIdx.x;  // 0..65535
    int b = t >> 10, h = t & 1023;
    float c = (s0 == 0) ? 0.f : cstate[t];
    const _Float16* gp = gates + (size_t)((b * chunk) >> 2) * 12288 + h * 4;
    float* op = out + (size_t)(b * SEQ + s0) * HS + h;
    float hv = 0.f;
    const int ng = chunk >> 2;               // row-groups of 4 steps
    int g4 = 0;
    for (; g4 + 1 < ng; g4 += 2) {
        f16x4 pv[2], fv[2], ov[2];
#pragma unroll
        for (int u = 0; u < 2; ++u) {
            const _Float16* q = gp + (size_t)(g4 + u) * 12288;
            pv[u] = *(const f16x4*)(q);
            fv[u] = *(const f16x4*)(q + 4096);
            ov[u] = *(const f16x4*)(q + 8192);
        }
#pragma unroll
        for (int u = 0; u < 2; ++u) {
#pragma unroll
            for (int r = 0; r < 4; ++r) {
                c = (float)fv[u][r] * c + (float)pv[u][r];
                float th = ftanh(c);
                hv = (float)ov[u][r] * th;
                op[(size_t)((g4 + u) * 4 + r) * HS] = hv;
            }
        }
    }
    for (; g4 < ng; ++g4) {                  // tail (odd ng)
        const _Float16* q = gp + (size_t)g4 * 12288;
        f16x4 pv = *(const f16x4*)(q);
        f16x4 fv = *(const f16x4*)(q + 4096);
        f16x4 ov = *(const f16x4*)(q + 8192);
#pragma unroll
        for (int r = 0; r < 4; ++r) {
            c = (float)fv[r] * c + (float)pv[r];
            float th = ftanh(c);
            hv = (float)ov[r] * th;
            op[(size_t)(g4 * 4 + r) * HS] = hv;
        }
    }
    cstate[t] = c;
    if (s0 + chunk == SEQ) {
        out[(size_t)BATCH * SEQ * HS + t] = hv;                      // h_T
        out[(size_t)BATCH * SEQ * HS + BATCH * HS + t] = c;          // c_T
    }
}

// ---------- launcher ----------
extern "C" void kernel_launch(void* const* d_in, const int* in_sizes, int n_in,
                              void* d_out, int out_size, void* d_ws, size_t ws_size,
                              hipStream_t stream) {
    const float* x    = (const float*)d_in[0];
    const float* U    = (const float*)d_in[1];
    const float* bias = (const float*)d_in[2];
    float* out = (float*)d_out;
    char*  ws  = (char*)d_ws;

    // ws layout
    unsigned short* Xb = (unsigned short*)ws;                   // 64MB  bf16 x
    unsigned short* Ut = (unsigned short*)(ws + 67108864);      // 8MB   bf16 U^T
    float* cstate      = (float*)(ws + 75497472);               // 256KB
    _Float16* gates    = (_Float16*)(ws + 75759616);            // chunk*0.375MB
    const size_t fixed = 75759616;

    int chunk = 512;
    while (chunk > 4 && fixed + (size_t)BATCH * chunk * 6144 > ws_size)
        chunk >>= 1;
    int lg2 = 31 - __builtin_clz(chunk);

    convert_x<<<2048, 256, 0, stream>>>(x, Xb, (long)BATCH * SEQ * HS / 8);
    transpose_u<<<4096, 256, 0, stream>>>(U, Ut);

    for (int s0 = 0; s0 < SEQ; s0 += chunk) {
        int mtiles = (BATCH * chunk) / 256;
        gemm_gates8<<<mtiles * 16, 512, 0, stream>>>(Xb, Ut, bias, gates, lg2, s0);
        lstm_recur<<<256, 256, 0, stream>>>(gates, out, cstate, chunk, s0);
    }
}